// Round 8
// baseline (219.984 us; speedup 1.0000x reference)
//
#include <hip/hip_runtime.h>

#define N_NODES 50000
#define N_EDGES 1600000
#define N_TOTAL (N_EDGES + N_NODES)   // edges + self loops
#define F_IN    32
#define HID     64
#define F_OUT   128
#define G       32                    // dst nodes per gather bucket
#define NB      1563                  // ceil(N_NODES / G) == number of bins now
#define CAP1_MAX 1408                 // per-bucket cap (mean ~1056 + ~11 sigma)
#define OVF_CAP 16384
#define W1WIN   4096                  // pass-1 window (edges per block)
#define NBINBLK  403                  // ceil(N_TOTAL / W1WIN) bin-role blocks
#define NNODEBLK 196                  // node-role blocks (256 nodes each)
#define NPAIR   782                   // ceil(NB / 2) scan pairs

// workspace layout (u32 units), ~14 MB max at CAP1_MAX:
#define OFF_QBF   0
#define OFF_CUR1  (N_NODES * 32)
#define OFF_OVFC  (OFF_CUR1 + NB * 16)
#define OFF_OVF   (OFF_OVFC + 16)
#define OFF_BIN   (OFF_OVF + OVF_CAP)
#define NCLR      (NB * 16 + 16)      // words to zero (cur1 + ovfc block)

typedef __attribute__((ext_vector_type(2))) _Float16 h2f;    // packed half2 (1 VGPR)
typedef __attribute__((ext_vector_type(8))) _Float16 half8;  // MFMA f16 frag (4 VGPRs)
typedef __attribute__((ext_vector_type(4))) float v4f;

__device__ __forceinline__ unsigned f2h2(float a, float b) {   // pack 2 f16 (RNE)
    h2f v;
    v.x = (_Float16)a; v.y = (_Float16)b;
    return __builtin_bit_cast(unsigned, v);
}

// relu(a - b) on packed f16 pairs: v_pk_add_f16(neg) + v_pk_max_f16
__device__ __forceinline__ unsigned hsubmax0(unsigned a, unsigned b) {
    h2f x = __builtin_bit_cast(h2f, a) - __builtin_bit_cast(h2f, b);
    h2f z = {(_Float16)0.f, (_Float16)0.f};
    x = __builtin_elementwise_max(x, z);
    return __builtin_bit_cast(unsigned, x);
}

__device__ __forceinline__ float h2lo(unsigned u) { return (float)__builtin_bit_cast(h2f, u).x; }
__device__ __forceinline__ float h2hi(unsigned u) { return (float)__builtin_bit_cast(h2f, u).y; }
__device__ __forceinline__ float f16r(float x)    { return (float)(_Float16)x; }

// Wave-local LDS handoff fence (per-wave staging only; no block barrier).
#define WAVE_FENCE() do { asm volatile("s_waitcnt lgkmcnt(0)" ::: "memory"); \
                          __builtin_amdgcn_sched_barrier(0); } while (0)

// ---------------------------------------------------------------------------
// Kernel Z: zero bucket cursors + overflow counter.
// ---------------------------------------------------------------------------
__global__ __launch_bounds__(256) void zero_kernel(unsigned* __restrict__ clr)
{
    const int i = blockIdx.x * 256 + threadIdx.x;
    if (i < NCLR) clr[i] = 0u;
}

// ---------------------------------------------------------------------------
// Kernel AB (fused, block-role split):
//   blocks [0, NBINBLK): DIRECT binning of a 4096-edge window into 1563
//     32-node buckets (d>>5). LDS-sort the window, flush each bucket run
//     with one global cursor atomicAdd + run store. Entry: (d << 16) | s.
//     This replaces the old two-pass bin+refine — refine is deleted.
//   blocks [NBINBLK, +NNODEBLK): node precompute Q'[n] = b1 + x_n@W1[0:32]
//     + pos_n@W1[32:35], packed f16 (4 lanes/node, acc[16] — VGPR-safe).
// ---------------------------------------------------------------------------
__global__ __launch_bounds__(1024) void bin_pre_kernel(
    const int* __restrict__ ei,
    unsigned* __restrict__ cur1, unsigned* __restrict__ bin1,
    unsigned* __restrict__ ovfc, unsigned* __restrict__ ovf, int cap1,
    const float* __restrict__ x, const float* __restrict__ pos,
    const float* __restrict__ W1, const float* __restrict__ b1,
    unsigned* __restrict__ qbf)
{
    __shared__ unsigned stage[W1WIN];       // 16 KB
    __shared__ unsigned hist[NB + 1];       // 6.3 KB (pad bin NB = 0)
    __shared__ unsigned startp[NB + 1];     // 6.3 KB
    __shared__ unsigned gbase[NB];          // 6.3 KB
    __shared__ unsigned wpart[16];
    __shared__ float    w1s[35 * HID + HID]; // 9 KB (node role)

    const int t = threadIdx.x, lane = t & 63;

    if (blockIdx.x >= NBINBLK) {
        // ---- node role (proven in rounds 5-7) ----
        for (int i = t; i < 35 * HID; i += 1024) w1s[i] = W1[i];
        if (t < HID) w1s[35 * HID + t] = b1[t];
        __syncthreads();

        const int n = (blockIdx.x - NBINBLK) * 256 + (t >> 2);
        const int sub = t & 3;                  // channel quarter [sub*16, +16)
        if (n >= N_NODES) return;

        const float4* x4 = (const float4*)(x + (long long)n * F_IN);
        const float4 xa = x4[sub * 2], xb = x4[sub * 2 + 1];
        const float xv[8] = {xa.x, xa.y, xa.z, xa.w, xb.x, xb.y, xb.z, xb.w};

        float acc[16];
        #pragma unroll
        for (int k = 0; k < 16; ++k) acc[k] = w1s[35 * HID + sub * 16 + k];

        #pragma unroll
        for (int c = 0; c < F_IN; ++c) {
            const float xm = __shfl(xv[c & 7], (lane & 60) | (c >> 3), 64);
            #pragma unroll
            for (int k = 0; k < 16; ++k)
                acc[k] = fmaf(xm, w1s[c * HID + sub * 16 + k], acc[k]);
        }
        #pragma unroll
        for (int a = 0; a < 3; ++a) {
            const float pp = pos[n * 3 + a];
            #pragma unroll
            for (int k = 0; k < 16; ++k)
                acc[k] = fmaf(pp, w1s[(F_IN + a) * HID + sub * 16 + k], acc[k]);
        }

        uint4* o4 = (uint4*)(qbf + (unsigned)n * 32u + (unsigned)sub * 8u);
        o4[0] = make_uint4(f2h2(acc[0], acc[1]),  f2h2(acc[2], acc[3]),
                           f2h2(acc[4], acc[5]),  f2h2(acc[6], acc[7]));
        o4[1] = make_uint4(f2h2(acc[8], acc[9]),  f2h2(acc[10], acc[11]),
                           f2h2(acc[12], acc[13]), f2h2(acc[14], acc[15]));
        return;
    }

    // ---- bin role ----
    const int wbase = blockIdx.x * W1WIN;

    for (int i = t; i < NB + 1; i += 1024) hist[i] = 0u;
    __syncthreads();

    unsigned ev[4]; int bv[4]; unsigned rv[4]; bool val[4];
    #pragma unroll
    for (int k = 0; k < 4; ++k) {
        const int idx = wbase + k * 1024 + t;
        val[k] = idx < N_TOTAL;
        if (val[k]) {
            int s, d;
            if (idx < N_EDGES) { s = ei[idx]; d = ei[N_EDGES + idx]; }
            else               { s = d = idx - N_EDGES; }    // self loop
            ev[k] = ((unsigned)d << 16) | (unsigned)s;
            bv[k] = d >> 5;
            rv[k] = atomicAdd(&hist[bv[k]], 1u);
        }
    }
    __syncthreads();

    // exclusive scan of hist[0..NB) via bin-pairs: thread t < NPAIR owns
    // bins (2t, 2t+1); wave-scan pair sums, 16 wave partials scanned by t0.
    unsigned h0 = 0, hpair = 0;
    if (t < NPAIR) { h0 = hist[2 * t]; hpair = h0 + hist[2 * t + 1]; }
    unsigned v = hpair;
    #pragma unroll
    for (int o = 1; o < 64; o <<= 1) {
        const unsigned u = __shfl_up(v, o, 64);
        if (lane >= o) v += u;
    }
    if (lane == 63) wpart[t >> 6] = v;
    __syncthreads();
    if (t == 0) {
        unsigned r = 0;
        #pragma unroll
        for (int i = 0; i < 16; ++i) { const unsigned c2 = wpart[i]; wpart[i] = r; r += c2; }
        startp[NB] = r;                      // total (pair 781 rewrites same value)
    }
    __syncthreads();
    if (t < NPAIR) {
        const unsigned bse = (v - hpair) + wpart[t >> 6];
        startp[2 * t]     = bse;
        startp[2 * t + 1] = bse + h0;
    }
    for (int i = t; i < NB; i += 1024)
        if (hist[i]) gbase[i] = atomicAdd(&cur1[i * 16], hist[i]);
    __syncthreads();

    #pragma unroll
    for (int k = 0; k < 4; ++k)
        if (val[k]) stage[startp[bv[k]] + rv[k]] = ev[k];
    __syncthreads();

    const unsigned total = startp[NB];
    for (unsigned i = t; i < total; i += 1024u) {
        const unsigned e = stage[i];
        const unsigned b = e >> 21;                 // bucket id = d >> 5
        const unsigned gp = gbase[b] + (i - startp[b]);
        if (gp < (unsigned)cap1) bin1[b * (unsigned)cap1 + gp] = e;
        else {
            const unsigned qo = atomicAdd(ovfc, 1u);
            if (qo < OVF_CAP) ovf[qo] = e;
        }
    }
}

// ---------------------------------------------------------------------------
// Kernel C: gather. Identical inner loop to round 7 (62 µs, VGPR 64, no
// spill). Bucket count read straight from the pass-1 cursor; dst-local
// dl = d & 31 computed from the entry.
// ---------------------------------------------------------------------------
__global__ __launch_bounds__(256, 4) void gather_kernel(
    const unsigned* __restrict__ qbf,   // [N,32] packed f16 Q'
    const float* __restrict__ pos,
    const unsigned* __restrict__ cur1,  // bucket cursors (counts), stride 16
    const unsigned* __restrict__ bkt,
    int cap1,
    const float* __restrict__ W1p,      // W1 rows 32..34, [3, 64]
    const float* __restrict__ W2, const float* __restrict__ b2,
    float* __restrict__ out)
{
    __shared__ unsigned aggs[(G + 1) * HID];  // 8448 B (+1 dump row)
    __shared__ unsigned rlds[G * 32];         // 4 KB: R[dst] f16 pairs, xor-swizzled
    __shared__ unsigned ast[4][64 * 16];      // 16 KB: per-wave A-stage (one k-half)

    const int t = threadIdx.x, lane = t & 63, w = t >> 6;
    const int q = lane >> 4, m15 = lane & 15;
    const int b = blockIdx.x;
    const unsigned cnt  = min(cur1[b * 16], (unsigned)cap1);
    const unsigned base = (unsigned)b * (unsigned)cap1;

    for (int i = t; i < (G + 1) * HID; i += 256) aggs[i] = 0u;
    for (int i = t; i < G * 32; i += 256) {             // R[dl][k] = pos_dl @ W1p
        const int dl = i >> 5, k2 = i & 31;
        const int node = b * G + dl;
        float v0 = 0.f, v1 = 0.f;
        if (node < N_NODES) {
            #pragma unroll
            for (int a = 0; a < 3; ++a) {
                const float pp = pos[node * 3 + a];
                v0 = fmaf(pp, W1p[a * HID + 2 * k2], v0);
                v1 = fmaf(pp, W1p[a * HID + 2 * k2 + 1], v1);
            }
        }
        rlds[(dl << 5) + ((((k2 >> 2) ^ (dl & 7)) << 2) | (k2 & 3))] = f2h2(v0, v1);
    }

    // W2^T B-fragments in registers (validated round 6/7).
    half8 bfr[2][2][2];
    #pragma unroll
    for (int h = 0; h < 2; ++h)
        #pragma unroll
        for (int ntl = 0; ntl < 2; ++ntl) {
            const int nn = (2 * h + ntl) * 16 + m15;
            #pragma unroll
            for (int ks = 0; ks < 2; ++ks) {
                half8 vv;
                #pragma unroll
                for (int j = 0; j < 4; ++j) {
                    const int ku = (ks * 4 + q) * 4 + j;    // k-pair index
                    vv[2 * j]     = (_Float16)W2[(2 * ku) * HID + nn];
                    vv[2 * j + 1] = (_Float16)W2[(2 * ku + 1) * HID + nn];
                }
                bfr[h][ntl][ks] = vv;
            }
        }
    float b2v[4];
    #pragma unroll
    for (int nt = 0; nt < 4; ++nt) b2v[nt] = b2[nt * 16 + m15];
    __syncthreads();

    unsigned* aw = ast[w];
    const int axw = ((lane >> 1) & 3) << 2;     // write-side chunk xor (u32 units)
    const int axr = ((m15 >> 1) & 3) << 2;      // read-side chunk xor
    const unsigned nit = (cnt + 255u) >> 8;     // block-uniform (cnt >= 1)

    #pragma unroll 1
    for (unsigned it = 0; it < nit; ++it) {
        const unsigned off = it * 256u + (unsigned)w * 64u;
        const unsigned rem = (off < cnt) ? min(64u, cnt - off) : 0u;
        const unsigned f = off + (unsigned)lane;
        unsigned pent = 0u;
        if (f < cnt) pent = bkt[base + f];
        const int s = (int)(pent & 0xFFFFu), dl = (int)((pent >> 16) & 31u);

        const uint4* qr = (const uint4*)(qbf + (unsigned)s * 32u);
        const int rbase = dl << 5, rx = dl & 7;

        half8 a0[4], a1[4];

        // ---- k-half 0: load qva, compute, stage, read frags ----
        uint4 qva[4];
        #pragma unroll
        for (int i = 0; i < 4; ++i) qva[i] = qr[i];

        uint4 hh0[4];
        #pragma unroll
        for (int j4 = 0; j4 < 4; ++j4) {
            const uint4 r4 = *(const uint4*)(rlds + rbase + ((j4 ^ rx) << 2));
            hh0[j4].x = hsubmax0(qva[j4].x, r4.x);
            hh0[j4].y = hsubmax0(qva[j4].y, r4.y);
            hh0[j4].z = hsubmax0(qva[j4].z, r4.z);
            hh0[j4].w = hsubmax0(qva[j4].w, r4.w);
        }
        // qva dead — issue second-half loads under the fence sequence below.
        uint4 qvb[4];
        #pragma unroll
        for (int i = 0; i < 4; ++i) qvb[i] = qr[i + 4];

        #pragma unroll
        for (int j4 = 0; j4 < 4; ++j4)
            *(uint4*)(aw + (lane << 4) + ((j4 << 2) ^ axw)) = hh0[j4];
        WAVE_FENCE();                   // stage writes -> cross-lane reads
        #pragma unroll
        for (int mt = 0; mt < 4; ++mt)
            a0[mt] = *(const half8*)(
                aw + ((mt * 16 + m15) << 4) + ((q << 2) ^ axr));
        WAVE_FENCE();                   // reads done -> next overwrite ok

        // ---- k-half 1 ----
        #pragma unroll
        for (int j4 = 0; j4 < 4; ++j4) {
            const uint4 r4 = *(const uint4*)(
                rlds + rbase + (((4 + j4) ^ rx) << 2));
            uint4 hh;
            hh.x = hsubmax0(qvb[j4].x, r4.x);
            hh.y = hsubmax0(qvb[j4].y, r4.y);
            hh.z = hsubmax0(qvb[j4].z, r4.z);
            hh.w = hsubmax0(qvb[j4].w, r4.w);
            *(uint4*)(aw + (lane << 4) + ((j4 << 2) ^ axw)) = hh;
        }
        WAVE_FENCE();
        #pragma unroll
        for (int mt = 0; mt < 4; ++mt)
            a1[mt] = *(const half8*)(
                aw + ((mt * 16 + m15) << 4) + ((q << 2) ^ axr));
        WAVE_FENCE();

        // ---- MFMA layer 2 + epilogue, two 32-channel halves ----
        #pragma unroll
        for (int h = 0; h < 2; ++h) {
            v4f c[4][2];
            #pragma unroll
            for (int mt = 0; mt < 4; ++mt)
                #pragma unroll
                for (int ntl = 0; ntl < 2; ++ntl) {
                    const float bb2 = b2v[2 * h + ntl];     // b2 as C-init
                    c[mt][ntl] = (v4f){bb2, bb2, bb2, bb2};
                }
            #pragma unroll
            for (int mt = 0; mt < 4; ++mt)
                #pragma unroll
                for (int ntl = 0; ntl < 2; ++ntl) {
                    c[mt][ntl] = __builtin_amdgcn_mfma_f32_16x16x32_f16(
                        a0[mt], bfr[h][ntl][0], c[mt][ntl], 0, 0, 0);
                    c[mt][ntl] = __builtin_amdgcn_mfma_f32_16x16x32_f16(
                        a1[mt], bfr[h][ntl][1], c[mt][ntl], 0, 0, 0);
                }
            #pragma unroll
            for (int mt = 0; mt < 4; ++mt)
                #pragma unroll
                for (int r = 0; r < 4; ++r) {
                    const int er = mt * 16 + q * 4 + r;
                    const int dv = __shfl(dl, er, 64);      // inline dst-local
                    const int dle = ((unsigned)er < rem) ? dv : G;  // dump row
                    const int ab = (dle << 6) + m15;
                    #pragma unroll
                    for (int ntl = 0; ntl < 2; ++ntl) {
                        const float hv = fmaxf(c[mt][ntl][r], 0.f);
                        atomicMax(&aggs[ab + (2 * h + ntl) * 16],
                                  __float_as_uint(hv));
                    }
                }
        }
    }

    __syncthreads();
    for (int i = t; i < G * HID; i += 256) {
        const int row = i >> 6, ch = i & 63, n = b * G + row;
        if (n < N_NODES)
            out[(long long)n * F_OUT + HID + ch] = __uint_as_float(aggs[i]);
    }
}

// ---------------------------------------------------------------------------
// Kernel D: overflow fixup (~0 edges in practice; correct for any count).
// Numerics match the MFMA path: h1 = relu(f16(Q' - f16(R))), W2 in f16.
// ---------------------------------------------------------------------------
__global__ __launch_bounds__(64) void ovf_kernel(
    const unsigned* __restrict__ qbf, const float* __restrict__ pos,
    const unsigned* __restrict__ ovfc, const unsigned* __restrict__ ovf,
    const float* __restrict__ W1p, const float* __restrict__ W2,
    const float* __restrict__ b2, unsigned* __restrict__ aggbits)
{
    const unsigned n = min(*ovfc, (unsigned)OVF_CAP);
    for (unsigned i = blockIdx.x * 64 + threadIdx.x; i < n; i += gridDim.x * 64) {
        const unsigned p = ovf[i];
        const int s = (int)(p & 0xFFFFu), d = (int)(p >> 16);
        float h1[HID];
        #pragma unroll 1
        for (int k = 0; k < HID; ++k) {
            const unsigned u = qbf[s * 32 + (k >> 1)];
            const float qp = (k & 1) ? h2hi(u) : h2lo(u);
            float r = 0.f;
            #pragma unroll 1
            for (int a = 0; a < 3; ++a) r = fmaf(pos[d * 3 + a], W1p[a * HID + k], r);
            h1[k] = fmaxf(f16r(qp - f16r(r)), 0.f);
        }
        unsigned* ap = aggbits + (long long)d * F_OUT + HID;
        #pragma unroll 1
        for (int k = 0; k < HID; ++k) {
            float a2 = b2[k];
            #pragma unroll 1
            for (int j = 0; j < HID; ++j)
                a2 = fmaf(h1[j], f16r(W2[j * HID + k]), a2);
            a2 = fmaxf(a2, 0.f);
            atomicMax(ap + k, __float_as_uint(a2));
        }
    }
}

// ---------------------------------------------------------------------------
// Kernel E: out[n] = agg[n] @ Wg + bg, in place (unchanged).
// ---------------------------------------------------------------------------
__global__ __launch_bounds__(256) void out_gemm_kernel(
    float* __restrict__ out,            // [N_NODES, 128]
    const float* __restrict__ Wg,       // [HID, F_OUT]
    const float* __restrict__ bg)       // [F_OUT]
{
    const int lane = threadIdx.x & 63;
    const int wave = blockIdx.x * (blockDim.x >> 6) + (threadIdx.x >> 6);
    const int nwav = gridDim.x * (blockDim.x >> 6);

    float w1r[HID], w2r[HID];
    #pragma unroll
    for (int j = 0; j < HID; ++j) {
        w1r[j] = Wg[j * F_OUT + lane];
        w2r[j] = Wg[j * F_OUT + 64 + lane];
    }
    const float bga = bg[lane];
    const float bgb = bg[64 + lane];

    for (int n = wave; n < N_NODES; n += nwav) {
        float* row = out + (long long)n * F_OUT;
        const float a = row[64 + lane];
        float y1 = bga, y2 = bgb;
        #pragma unroll
        for (int j = 0; j < HID; ++j) {
            const float aj = __shfl(a, j, 64);
            y1 = fmaf(aj, w1r[j], y1);
            y2 = fmaf(aj, w2r[j], y2);
        }
        row[lane]      = y1;
        row[64 + lane] = y2;
    }
}

extern "C" void kernel_launch(void* const* d_in, const int* in_sizes, int n_in,
                              void* d_out, int out_size, void* d_ws, size_t ws_size,
                              hipStream_t stream) {
    const float* x   = (const float*)d_in[0];
    const float* pos = (const float*)d_in[1];
    const int*   ei  = (const int*)d_in[2];    // harness delivers integers as int32
    const float* W1  = (const float*)d_in[3];
    const float* b1  = (const float*)d_in[4];
    const float* W2  = (const float*)d_in[5];
    const float* b2  = (const float*)d_in[6];
    const float* Wg  = (const float*)d_in[7];
    const float* bg  = (const float*)d_in[8];
    float* out = (float*)d_out;

    unsigned* ws    = (unsigned*)d_ws;
    unsigned* qbf   = ws + OFF_QBF;
    unsigned* cur1  = ws + OFF_CUR1;
    unsigned* ovfc  = ws + OFF_OVFC;
    unsigned* ovf   = ws + OFF_OVF;
    unsigned* bin1  = ws + OFF_BIN;

    // per-bucket capacity from available workspace (overflow path correct
    // for any cap; floor 1152 fits the known-good ~14.5 MB ws footprint)
    long long avail = (long long)(ws_size / 4) - OFF_BIN;
    int cap1 = (int)(avail / NB);
    if (cap1 > CAP1_MAX) cap1 = CAP1_MAX;
    if (cap1 < 1152) cap1 = 1152;

    zero_kernel<<<(NCLR + 255) / 256, 256, 0, stream>>>(cur1);
    bin_pre_kernel<<<NBINBLK + NNODEBLK, 1024, 0, stream>>>(
        ei, cur1, bin1, ovfc, ovf, cap1, x, pos, W1, b1, qbf);
    gather_kernel<<<NB, 256, 0, stream>>>(
        qbf, pos, cur1, bin1, cap1, W1 + F_IN * HID, W2, b2, out);
    ovf_kernel<<<32, 64, 0, stream>>>(
        qbf, pos, ovfc, ovf, W1 + F_IN * HID, W2, b2, (unsigned*)out);
    out_gemm_kernel<<<512, 256, 0, stream>>>(out, Wg, bg);
}